// Round 10
// baseline (71.037 us; speedup 1.0000x reference)
//
#include <hip/hip_runtime.h>
#include <math.h>

// B=4096, N=196, D=32, M=12, NH=4, DH=8, H=W=14
// outputs (flat f32): Z[4096*32] | A_maps[4096*12*196] | head_energy[4096*12*4] | S[4096*12*32] | topk_mass[4096*12]
// ws layout (bytes): G16 fp16[48*32] @0 | rpbc32 f32[48*208] @4096 (pad cols 196..207 = -60000)

typedef float f32x4 __attribute__((ext_vector_type(4)));
typedef float f32x2 __attribute__((ext_vector_type(2)));
typedef _Float16 h2  __attribute__((ext_vector_type(2)));
typedef _Float16 h4v __attribute__((ext_vector_type(4)));
typedef _Float16 h8  __attribute__((ext_vector_type(8)));
typedef __fp16 fp16x2 __attribute__((ext_vector_type(2)));

__device__ __forceinline__ h2 cvt_pk(float a, float b){
  fp16x2 r = __builtin_amdgcn_cvt_pkrtz(a, b);
  return __builtin_bit_cast(h2, r);
}

__device__ __forceinline__ float dot4(float4 a, float4 b){
  return a.x*b.x + a.y*b.y + a.z*b.z + a.w*b.w;
}

// ---- DPP int-max reduction (topk) ----
template<int CTRL>
__device__ __forceinline__ int idpp(int x, int id){
  return __builtin_amdgcn_update_dpp(id, x, CTRL, 0xF, 0xF, false);
}
__device__ __forceinline__ int wimax_all(int x){
  const int ID = 0;
  x = max(x, idpp<0x111>(x, ID));
  x = max(x, idpp<0x112>(x, ID));
  x = max(x, idpp<0x114>(x, ID));
  x = max(x, idpp<0x118>(x, ID));
  x = max(x, idpp<0x142>(x, ID));
  x = max(x, idpp<0x143>(x, ID));
  return __builtin_amdgcn_readlane(x, 63);
}

// ---------------- prologue: G16 fp16; rpbc32 f32 padded ----------------
__global__ void prologue_kernel(const float* __restrict__ Q, const float* __restrict__ Wq,
                                const float* __restrict__ Wk, const float* __restrict__ rpb,
                                const float* __restrict__ qc, const float* __restrict__ kc,
                                _Float16* __restrict__ G16, float* __restrict__ rpbc32)
{
  __shared__ float Qp[384];
  const int tid = threadIdx.x;
  const int bid = blockIdx.x;

  if (bid == 0){
    for (int i = tid; i < 384; i += 256){
      int m = i >> 5, d = i & 31;
      float a = 0.f;
      #pragma unroll
      for (int c = 0; c < 32; ++c) a += Q[m*32+c] * Wq[d*32+c];
      Qp[i] = a;
    }
    __syncthreads();
    const float s = 0.35355339059327373f; // 1/sqrt(8)
    for (int i = tid; i < 1536; i += 256){
      int hm = i >> 5, c = i & 31;
      int hh = hm / 12, mm = hm - 12*hh;
      float a = 0.f;
      #pragma unroll
      for (int dh = 0; dh < 8; ++dh) a += Qp[mm*32 + hh*8 + dh] * Wk[(hh*8+dh)*32 + c];
      G16[i] = (_Float16)(a * s);
    }
  }
  int i = bid*256 + tid;
  if (i < 9984){                       // 48 rows x 208 cols
    int mh = i / 208, n = i - mh*208;
    float v;
    if (n < 196){
      int hh = mh / 12, mm = mh - 12*hh;
      float dy = qc[2*mm]   - kc[2*n];
      float dx = qc[2*mm+1] - kc[2*n+1];
      int iy = (int)rintf(dy) + 13; iy = iy < 0 ? 0 : (iy > 26 ? 26 : iy);
      int ix = (int)rintf(dx) + 13; ix = ix < 0 ? 0 : (ix > 26 ? 26 : ix);
      v = rpb[hh*729 + iy*27 + ix];
    } else {
      v = -60000.0f;                   // pad: exp -> 0, never the max
    }
    rpbc32[i] = v;
  }
}

// TT layout: subtiled [nb][cb][4][16] halfs, nb-stride 128 halfs (UNPADDED: every
// [4][16] subtile is 128-B aligned, required by ds_read_b64_tr_b16 tile addressing).
// T[n][c] at (n>>2)*128 + (c>>4)*64 + (n&3)*16 + (c&15).  208 rows (52 nb).
__device__ __forceinline__ int ttoff(int n, int c8){   // c8 = chunk of 8 halfs
  return (n>>2)*128 + ((c8>>1)<<6) + ((n&3)<<4) + ((c8&1)<<3);
}

// ---------------- fully fused kernel: one block per batch element ----------------
__global__ __launch_bounds__(256, 5) void fused_main(
    const float* __restrict__ T, const float* __restrict__ Wv, const float* __restrict__ Wp,
    const float* __restrict__ bp, const _Float16* __restrict__ G16,
    const float* __restrict__ rpbc32, float* __restrict__ out)
{
  // TT:13312B @0 | As:19200B+32B guard @13312.  After the post-E/C barrier TT is dead:
  // U [48][36] f32 @0 (6912B) | Ss [384] f32 @7168 (1536B).
  // Total LDS 32544B -> rounds to 32768 -> 5 blocks/CU (20 waves/CU).
  __shared__ __align__(128) char smem[32544];
  _Float16* TT = (_Float16*)smem;                 // [52 nb][128] halfs (rows 0..207)
  _Float16* As = (_Float16*)(smem + 13312);       // [48][200] halfs + 16-half guard
  float*    U  = (float*)smem;                    // [48][36] f32 (alias, after barrier)
  float*    Ss = (float*)(smem + 7168);           // [384] f32 (alias)

  const int b    = blockIdx.x;
  const int tid  = threadIdx.x;
  const int lane = tid & 63;
  const int h    = tid >> 6;       // wave id
  const int r15  = lane & 15;
  const int g    = lane >> 4;

  float* outZ = out;                       // [4096][32]
  float* outA = out + 131072;              // [4096][12][196]
  float* outE = out + 9764864;             // [4096][12][4]
  float* outS = out + 9961472;             // [4096][12][32]
  float* outK = out + 11534336;            // [4096][12]

  // ---- A: stage T -> fp16 subtiled LDS (rows 0..207; rows 196..207 zero) ----
  const float* Tb = T + (size_t)b*6272;
  #pragma unroll
  for (int ii = 0; ii < 3; ++ii){
    int i = tid + ii*256;                  // n < 192
    int n = i >> 2, c8 = i & 3;
    const f32x4* src = (const f32x4*)(Tb + n*32 + c8*8);
    f32x4 v0 = __builtin_nontemporal_load(src);
    f32x4 v1 = __builtin_nontemporal_load(src + 1);
    h2 p0 = cvt_pk(v0[0], v0[1]);
    h2 p1 = cvt_pk(v0[2], v0[3]);
    h2 p2 = cvt_pk(v1[0], v1[1]);
    h2 p3 = cvt_pk(v1[2], v1[3]);
    h4v lo = __builtin_shufflevector(p0, p1, 0,1,2,3);
    h4v hi = __builtin_shufflevector(p2, p3, 0,1,2,3);
    *(h8*)&TT[ttoff(n, c8)] = __builtin_shufflevector(lo, hi, 0,1,2,3,4,5,6,7);
  }
  if (tid < 64){
    int i = 768 + tid;                     // n = 192..207
    int n = i >> 2, c8 = i & 3;
    h8 hv = {0,0,0,0,0,0,0,0};
    if (n < 196){
      const f32x4* src = (const f32x4*)(Tb + n*32 + c8*8);
      f32x4 v0 = __builtin_nontemporal_load(src);
      f32x4 v1 = __builtin_nontemporal_load(src + 1);
      h2 p0 = cvt_pk(v0[0], v0[1]);
      h2 p1 = cvt_pk(v0[2], v0[3]);
      h2 p2 = cvt_pk(v1[0], v1[1]);
      h2 p3 = cvt_pk(v1[2], v1[3]);
      h4v lo = __builtin_shufflevector(p0, p1, 0,1,2,3);
      h4v hi = __builtin_shufflevector(p2, p3, 0,1,2,3);
      hv = __builtin_shufflevector(lo, hi, 0,1,2,3,4,5,6,7);
    }
    *(h8*)&TT[ttoff(n, c8)] = hv;
  }
  // zero the 16-half guard after As row 47 (kills the arow=47,g>=2 tail NaN path)
  if (tid < 2){
    h8 z = {0,0,0,0,0,0,0,0};
    *(h8*)&As[9600 + tid*8] = z;
  }

  // B-frag (G row) + rpb f32 accumulator init (global loads before the barrier)
  const int mhB = h*12 + (r15 < 12 ? r15 : 11);
  h8 bfrag = *(const h8*)(G16 + mhB*32 + g*8);
  f32x4 acc[13];
  #pragma unroll
  for (int t = 0; t < 13; ++t)
    acc[t] = *(const f32x4*)(rpbc32 + mhB*208 + t*16 + g*4);
  __syncthreads();

  // ---- B: content via MFMA.  C[n][mh]: n = t*16 + g*4 + r, mh col = r15. ----
  const int rowoff = ((r15>>2)*128) + ((r15&3)<<4) + ((g>>1)<<6) + ((g&1)<<3);
  #pragma unroll
  for (int t = 0; t < 13; ++t){
    h8 af = *(const h8*)&TT[rowoff + t*512];
    acc[t] = __builtin_amdgcn_mfma_f32_16x16x32_f16(af, bfrag, acc[t], 0, 0, 0);
  }

  // per-lane softmax over 52 n-values + cross-lane combine (lanes sharing r15)
  float mx = -1e30f;
  #pragma unroll
  for (int t = 0; t < 13; ++t)
    mx = fmaxf(mx, fmaxf(fmaxf(acc[t][0], acc[t][1]), fmaxf(acc[t][2], acc[t][3])));
  mx = fmaxf(mx, __shfl_xor(mx, 16));
  mx = fmaxf(mx, __shfl_xor(mx, 32));
  float se = 0.f, te = 0.f;
  #pragma unroll
  for (int t = 0; t < 13; ++t){
    #pragma unroll
    for (int r = 0; r < 4; ++r){
      float d = acc[t][r] - mx;
      float e = __expf(d);
      se += e; te += d*e;
      acc[t][r] = e;
    }
  }
  se += __shfl_xor(se, 16); se += __shfl_xor(se, 32);
  te += __shfl_xor(te, 16); te += __shfl_xor(te, 32);
  const float inv = 1.f / se;
  if (r15 < 12){
    #pragma unroll
    for (int t = 0; t < 13; ++t){
      if (t == 12){
        // cols 196..199 (g==1) are real zeros needed by the E tail; skip g>=2 (beyond stride)
        if (g >= 2) continue;
      }
      h2 w0 = cvt_pk(acc[t][0]*inv, acc[t][1]*inv);
      h2 w1 = cvt_pk(acc[t][2]*inv, acc[t][3]*inv);
      *(h4v*)&As[mhB*200 + t*16 + g*4] = __builtin_shufflevector(w0, w1, 0,1,2,3);
    }
    if (g == 0){
      const float LOGN_INV = 0.18946127f; // 1/ln(196)
      outE[(size_t)b*48 + r15*4 + h] = 1.0f + (te*inv - __logf(se)) * LOGN_INV;
    }
  }
  __syncthreads();

  // ---- E: U[mh][c] = sum_n A[mh][n]*T[n][c] via MFMA + ds_read_b64_tr_b16 (waves 0..2).
  //      Rows 0..191 via 6 x (16x16x32); rows 192..207 via one 16x16x16 tail.
  //      Result stays in registers; written to LDS only after TT is dead. ----
  f32x4 u0 = {0,0,0,0}, u1 = {0,0,0,0};
  if (h < 3){
    const int arow = h*16 + r15;
    unsigned A0 = (unsigned)(size_t)&TT[0] + (unsigned)(g*512 + r15*8);
    #pragma unroll
    for (int ks = 0; ks < 6; ++ks){
      h8 af = *(const h8*)&As[arow*200 + ks*32 + g*8];
      h4v t0, t1, t2, t3;
      // B[k=n][j=c]: lane (r15,g) gets cols c=r15 (+16) of rows n=ks*32+g*8+0..7
      asm volatile("ds_read_b64_tr_b16 %0, %1"            : "=v"(t0) : "v"(A0));  // nb+0, cb0
      asm volatile("ds_read_b64_tr_b16 %0, %1 offset:256" : "=v"(t1) : "v"(A0));  // nb+1, cb0
      asm volatile("ds_read_b64_tr_b16 %0, %1 offset:128" : "=v"(t2) : "v"(A0));  // nb+0, cb1
      asm volatile("ds_read_b64_tr_b16 %0, %1 offset:384" : "=v"(t3) : "v"(A0));  // nb+1, cb1
      asm volatile("s_waitcnt lgkmcnt(0)" ::: "memory");
      __builtin_amdgcn_sched_barrier(0);
      h8 b0 = __builtin_shufflevector(t0, t1, 0,1,2,3,4,5,6,7);
      h8 b1 = __builtin_shufflevector(t2, t3, 0,1,2,3,4,5,6,7);
      u0 = __builtin_amdgcn_mfma_f32_16x16x32_f16(af, b0, u0, 0, 0, 0);
      u1 = __builtin_amdgcn_mfma_f32_16x16x32_f16(af, b1, u1, 0, 0, 0);
      A0 += 2048;   // next 8 nb-blocks (32 rows)
    }
    // tail: n = 192..207 (A cols 196..199 are zeros; 200..207 read finite neighbors x TT zeros)
    h4v afT = *(const h4v*)&As[arow*200 + 192 + g*4];
    unsigned At = (unsigned)(size_t)&TT[0] + (unsigned)(12288 + g*256 + r15*8);
    h4v bt0, bt1;
    asm volatile("ds_read_b64_tr_b16 %0, %1"            : "=v"(bt0) : "v"(At));
    asm volatile("ds_read_b64_tr_b16 %0, %1 offset:128" : "=v"(bt1) : "v"(At));
    asm volatile("s_waitcnt lgkmcnt(0)" ::: "memory");
    __builtin_amdgcn_sched_barrier(0);
    u0 = __builtin_amdgcn_mfma_f32_16x16x16f16(afT, bt0, u0, 0, 0, 0);
    u1 = __builtin_amdgcn_mfma_f32_16x16x16f16(afT, bt1, u1, 0, 0, 0);
  }

  // ---- C: A_avg, A_maps, top-9 mass. lane -> 4 consecutive n; 3 interleaved DPP chains ----
  {
    const bool act = (lane < 49);
    const int nb4 = lane * 4;
    int K00=0,K01=0,K02=0,K03=0, K10=0,K11=0,K12=0,K13=0, K20=0,K21=0,K22=0,K23=0;
    float mass0=0.f, mass1=0.f, mass2=0.f;
    const int m0 = h, m1 = h+4, m2 = h+8;

    #pragma unroll
    for (int mi = 0; mi < 3; ++mi){
      int m = (mi==0) ? m0 : ((mi==1) ? m1 : m2);
      if (act){
        h4v s0 = *(const h4v*)&As[(     m)*200 + nb4];
        h4v s1 = *(const h4v*)&As[(12 + m)*200 + nb4];
        h4v s2 = *(const h4v*)&As[(24 + m)*200 + nb4];
        h4v s3 = *(const h4v*)&As[(36 + m)*200 + nb4];
        h4v sh = (s0 + s1) + (s2 + s3);          // packed fp16 adds
        float a0 = 0.25f*(float)sh[0], a1 = 0.25f*(float)sh[1];
        float a2 = 0.25f*(float)sh[2], a3 = 0.25f*(float)sh[3];
        float* amrow = outA + (size_t)b*2352 + m*196 + nb4;
        f32x2 o0 = {a0, a1}, o1 = {a2, a3};
        __builtin_nontemporal_store(o0, (f32x2*)amrow);
        __builtin_nontemporal_store(o1, (f32x2*)(amrow + 2));
        int kk0 = (__builtin_bit_cast(int, a0) & ~0xFF) | (lane << 2) | 0;
        int kk1 = (__builtin_bit_cast(int, a1) & ~0xFF) | (lane << 2) | 1;
        int kk2 = (__builtin_bit_cast(int, a2) & ~0xFF) | (lane << 2) | 2;
        int kk3 = (__builtin_bit_cast(int, a3) & ~0xFF) | (lane << 2) | 3;
        if (mi == 0){ K00=kk0; K01=kk1; K02=kk2; K03=kk3; }
        else if (mi == 1){ K10=kk0; K11=kk1; K12=kk2; K13=kk3; }
        else { K20=kk0; K21=kk1; K22=kk2; K23=kk3; }
      }
    }
    #pragma unroll
    for (int k = 0; k < 9; ++k){
      int g0 = wimax_all(max(max(K00,K01), max(K02,K03)));
      int g1 = wimax_all(max(max(K10,K11), max(K12,K13)));
      int g2 = wimax_all(max(max(K20,K21), max(K22,K23)));
      mass0 += __builtin_bit_cast(float, g0 & ~0xFF);
      mass1 += __builtin_bit_cast(float, g1 & ~0xFF);
      mass2 += __builtin_bit_cast(float, g2 & ~0xFF);
      if (lane == ((g0 >> 2) & 63)){
        int q = g0 & 3;
        if (q==0) K00=0; else if (q==1) K01=0; else if (q==2) K02=0; else K03=0;
      }
      if (lane == ((g1 >> 2) & 63)){
        int q = g1 & 3;
        if (q==0) K10=0; else if (q==1) K11=0; else if (q==2) K12=0; else K13=0;
      }
      if (lane == ((g2 >> 2) & 63)){
        int q = g2 & 3;
        if (q==0) K20=0; else if (q==1) K21=0; else if (q==2) K22=0; else K23=0;
      }
    }
    if (lane == 0){
      __builtin_nontemporal_store(mass0, outK + (size_t)b*12 + m0);
      __builtin_nontemporal_store(mass1, outK + (size_t)b*12 + m1);
      __builtin_nontemporal_store(mass2, outK + (size_t)b*12 + m2);
    }
  }
  __syncthreads();   // all TT reads (tr + content) done; TT is dead

  // ---- U-write: spill register U into the dead TT region ----
  if (h < 3){
    #pragma unroll
    for (int r = 0; r < 4; ++r){
      U[(h*16 + g*4 + r)*36 + r15]      = u0[r];
      U[(h*16 + g*4 + r)*36 + 16 + r15] = u1[r];
    }
  }
  __syncthreads();

  // ---- S: S[m][d] = sum_c U[(d>>3)*12+m][c] * Wv[d][c]; write S out + Ss(LDS) ----
  for (int md = tid; md < 384; md += 256){
    int m = md >> 5, d = md & 31, hh = d >> 3;
    const float4* Urow = (const float4*)(U + (hh*12 + m)*36);
    const float4* Wvr  = (const float4*)(Wv + d*32);
    float a = 0.f;
    #pragma unroll
    for (int q = 0; q < 8; ++q) a += dot4(Urow[q], Wvr[q]);
    Ss[md] = a;
    __builtin_nontemporal_store(a, outS + (size_t)b*384 + md);
  }
  __syncthreads();

  // ---- Z: Z[d] = bp[d] + sum_j Wp[d][j] * Ss[j]  (8-lane shuffle reduce) ----
  {
    int d = tid >> 3, j4 = tid & 7;
    const float4* Wp4 = (const float4*)(Wp + d*384);
    const float4* Ss4 = (const float4*)Ss;
    float a = 0.f;
    #pragma unroll
    for (int jj = 0; jj < 12; ++jj){
      int j = j4 + jj*8;
      a += dot4(Wp4[j], Ss4[j]);
    }
    a += __shfl_xor(a, 1);
    a += __shfl_xor(a, 2);
    a += __shfl_xor(a, 4);
    if (j4 == 0)
      __builtin_nontemporal_store(bp[d] + a, outZ + (size_t)b*32 + d);
  }
}

extern "C" void kernel_launch(void* const* d_in, const int* in_sizes, int n_in,
                              void* d_out, int out_size, void* d_ws, size_t ws_size,
                              hipStream_t stream)
{
  const float* T    = (const float*)d_in[0];
  const float* Q    = (const float*)d_in[1];
  const float* Wq   = (const float*)d_in[2];
  const float* Wk   = (const float*)d_in[3];
  const float* Wv   = (const float*)d_in[4];
  const float* Wp   = (const float*)d_in[5];
  const float* bp   = (const float*)d_in[6];
  const float* rpb  = (const float*)d_in[7];
  const float* qc   = (const float*)d_in[8];
  const float* kc   = (const float*)d_in[9];
  _Float16* G16  = (_Float16*)d_ws;
  float* rpbc32  = (float*)((char*)d_ws + 4096);
  float* outp = (float*)d_out;

  prologue_kernel<<<40, 256, 0, stream>>>(Q, Wq, Wk, rpb, qc, kc, G16, rpbc32);
  fused_main<<<4096, 256, 0, stream>>>(T, Wv, Wp, bp, G16, rpbc32, outp);
}

// Round 11
// 70.992 us; speedup vs baseline: 1.0006x; 1.0006x over previous
//
#include <hip/hip_runtime.h>
#include <math.h>

// B=4096, N=196, D=32, M=12, NH=4, DH=8, H=W=14
// outputs (flat f32): Z[4096*32] | A_maps[4096*12*196] | head_energy[4096*12*4] | S[4096*12*32] | topk_mass[4096*12]
// ws layout (bytes): G16 fp16[48*32] @0 | rpbc32 f32[48*208] @4096 (pad cols 196..207 = -60000)

typedef float f32x4 __attribute__((ext_vector_type(4)));
typedef float f32x2 __attribute__((ext_vector_type(2)));
typedef _Float16 h2  __attribute__((ext_vector_type(2)));
typedef _Float16 h4v __attribute__((ext_vector_type(4)));
typedef _Float16 h8  __attribute__((ext_vector_type(8)));
typedef __fp16 fp16x2 __attribute__((ext_vector_type(2)));

__device__ __forceinline__ h2 cvt_pk(float a, float b){
  fp16x2 r = __builtin_amdgcn_cvt_pkrtz(a, b);
  return __builtin_bit_cast(h2, r);
}

__device__ __forceinline__ float dot4(float4 a, float4 b){
  return a.x*b.x + a.y*b.y + a.z*b.z + a.w*b.w;
}

// LDS-only barrier: waits ds ops but leaves global (nontemporal) stores in flight.
// All cross-wave data exchange in fused_main is through LDS, so vmcnt drain is unneeded.
__device__ __forceinline__ void barrier_lds(){
  asm volatile("s_waitcnt lgkmcnt(0)" ::: "memory");
  __builtin_amdgcn_s_barrier();
  asm volatile("" ::: "memory");
}

// ---- DPP int-max reduction (topk) ----
template<int CTRL>
__device__ __forceinline__ int idpp(int x, int id){
  return __builtin_amdgcn_update_dpp(id, x, CTRL, 0xF, 0xF, false);
}
__device__ __forceinline__ int wimax_all(int x){
  const int ID = 0;
  x = max(x, idpp<0x111>(x, ID));
  x = max(x, idpp<0x112>(x, ID));
  x = max(x, idpp<0x114>(x, ID));
  x = max(x, idpp<0x118>(x, ID));
  x = max(x, idpp<0x142>(x, ID));
  x = max(x, idpp<0x143>(x, ID));
  return __builtin_amdgcn_readlane(x, 63);
}

// ---------------- prologue: G16 fp16; rpbc32 f32 padded ----------------
__global__ void prologue_kernel(const float* __restrict__ Q, const float* __restrict__ Wq,
                                const float* __restrict__ Wk, const float* __restrict__ rpb,
                                const float* __restrict__ qc, const float* __restrict__ kc,
                                _Float16* __restrict__ G16, float* __restrict__ rpbc32)
{
  __shared__ float Qp[384];
  const int tid = threadIdx.x;
  const int bid = blockIdx.x;

  if (bid == 0){
    for (int i = tid; i < 384; i += 256){
      int m = i >> 5, d = i & 31;
      float a = 0.f;
      #pragma unroll
      for (int c = 0; c < 32; ++c) a += Q[m*32+c] * Wq[d*32+c];
      Qp[i] = a;
    }
    __syncthreads();
    const float s = 0.35355339059327373f; // 1/sqrt(8)
    for (int i = tid; i < 1536; i += 256){
      int hm = i >> 5, c = i & 31;
      int hh = hm / 12, mm = hm - 12*hh;
      float a = 0.f;
      #pragma unroll
      for (int dh = 0; dh < 8; ++dh) a += Qp[mm*32 + hh*8 + dh] * Wk[(hh*8+dh)*32 + c];
      G16[i] = (_Float16)(a * s);
    }
  }
  int i = bid*256 + tid;
  if (i < 9984){                       // 48 rows x 208 cols
    int mh = i / 208, n = i - mh*208;
    float v;
    if (n < 196){
      int hh = mh / 12, mm = mh - 12*hh;
      float dy = qc[2*mm]   - kc[2*n];
      float dx = qc[2*mm+1] - kc[2*n+1];
      int iy = (int)rintf(dy) + 13; iy = iy < 0 ? 0 : (iy > 26 ? 26 : iy);
      int ix = (int)rintf(dx) + 13; ix = ix < 0 ? 0 : (ix > 26 ? 26 : ix);
      v = rpb[hh*729 + iy*27 + ix];
    } else {
      v = -60000.0f;                   // pad: exp -> 0, never the max
    }
    rpbc32[i] = v;
  }
}

// TT layout: subtiled [nb][cb][4][16] halfs, nb-stride 128 halfs (UNPADDED: every
// [4][16] subtile is 128-B aligned, required by ds_read_b64_tr_b16 tile addressing).
// T[n][c] at (n>>2)*128 + (c>>4)*64 + (n&3)*16 + (c&15).  208 rows (52 nb).
__device__ __forceinline__ int ttoff(int n, int c8){   // c8 = chunk of 8 halfs
  return (n>>2)*128 + ((c8>>1)<<6) + ((n&3)<<4) + ((c8&1)<<3);
}

#define TRRD(dst, base, off) \
  asm volatile("ds_read_b64_tr_b16 %0, %1 offset:" #off : "=v"(dst) : "v"(base))
#define SH8(a, b) __builtin_shufflevector(a, b, 0,1,2,3,4,5,6,7)

// ---------------- fully fused kernel: one block per batch element ----------------
__global__ __launch_bounds__(256, 4) void fused_main(
    const float* __restrict__ T, const float* __restrict__ Wv, const float* __restrict__ Wp,
    const float* __restrict__ bp, const _Float16* __restrict__ G16,
    const float* __restrict__ rpbc32, float* __restrict__ out)
{
  // TT:13312B @0 | As:19200B+32B guard @13312.  After the post-E/C barrier TT is dead:
  // U [48][36] f32 @0 (6912B) | Ss [384] f32 @7168 (1536B).
  __shared__ __align__(128) char smem[32544];
  _Float16* TT = (_Float16*)smem;                 // [52 nb][128] halfs (rows 0..207)
  _Float16* As = (_Float16*)(smem + 13312);       // [48][200] halfs + 16-half guard
  float*    U  = (float*)smem;                    // [48][36] f32 (alias, after barrier)
  float*    Ss = (float*)(smem + 7168);           // [384] f32 (alias)

  const int b    = blockIdx.x;
  const int tid  = threadIdx.x;
  const int lane = tid & 63;
  const int h    = tid >> 6;       // wave id
  const int r15  = lane & 15;
  const int g    = lane >> 4;

  float* outZ = out;                       // [4096][32]
  float* outA = out + 131072;              // [4096][12][196]
  float* outE = out + 9764864;             // [4096][12][4]
  float* outS = out + 9961472;             // [4096][12][32]
  float* outK = out + 11534336;            // [4096][12]

  // ---- A: stage T -> fp16 subtiled LDS (rows 0..207; rows 196..207 zero) ----
  const float* Tb = T + (size_t)b*6272;
  #pragma unroll
  for (int ii = 0; ii < 3; ++ii){
    int i = tid + ii*256;                  // n < 192
    int n = i >> 2, c8 = i & 3;
    const f32x4* src = (const f32x4*)(Tb + n*32 + c8*8);
    f32x4 v0 = __builtin_nontemporal_load(src);
    f32x4 v1 = __builtin_nontemporal_load(src + 1);
    h2 p0 = cvt_pk(v0[0], v0[1]);
    h2 p1 = cvt_pk(v0[2], v0[3]);
    h2 p2 = cvt_pk(v1[0], v1[1]);
    h2 p3 = cvt_pk(v1[2], v1[3]);
    h4v lo = __builtin_shufflevector(p0, p1, 0,1,2,3);
    h4v hi = __builtin_shufflevector(p2, p3, 0,1,2,3);
    *(h8*)&TT[ttoff(n, c8)] = __builtin_shufflevector(lo, hi, 0,1,2,3,4,5,6,7);
  }
  if (tid < 64){
    int i = 768 + tid;                     // n = 192..207
    int n = i >> 2, c8 = i & 3;
    h8 hv = {0,0,0,0,0,0,0,0};
    if (n < 196){
      const f32x4* src = (const f32x4*)(Tb + n*32 + c8*8);
      f32x4 v0 = __builtin_nontemporal_load(src);
      f32x4 v1 = __builtin_nontemporal_load(src + 1);
      h2 p0 = cvt_pk(v0[0], v0[1]);
      h2 p1 = cvt_pk(v0[2], v0[3]);
      h2 p2 = cvt_pk(v1[0], v1[1]);
      h2 p3 = cvt_pk(v1[2], v1[3]);
      h4v lo = __builtin_shufflevector(p0, p1, 0,1,2,3);
      h4v hi = __builtin_shufflevector(p2, p3, 0,1,2,3);
      hv = __builtin_shufflevector(lo, hi, 0,1,2,3,4,5,6,7);
    }
    *(h8*)&TT[ttoff(n, c8)] = hv;
  }
  // zero the 16-half guard after As row 47 (kills the arow=47,g>=2 tail NaN path)
  if (tid < 2){
    h8 z = {0,0,0,0,0,0,0,0};
    *(h8*)&As[9600 + tid*8] = z;
  }

  // B-frag (G row) + rpb f32 accumulator init (global loads before the barrier)
  const int mhB = h*12 + (r15 < 12 ? r15 : 11);
  h8 bfrag = *(const h8*)(G16 + mhB*32 + g*8);
  f32x4 acc[13];
  #pragma unroll
  for (int t = 0; t < 13; ++t)
    acc[t] = *(const f32x4*)(rpbc32 + mhB*208 + t*16 + g*4);
  barrier_lds();

  // ---- B: content via MFMA.  C[n][mh]: n = t*16 + g*4 + r, mh col = r15. ----
  const int rowoff = ((r15>>2)*128) + ((r15&3)<<4) + ((g>>1)<<6) + ((g&1)<<3);
  #pragma unroll
  for (int t = 0; t < 13; ++t){
    h8 af = *(const h8*)&TT[rowoff + t*512];
    acc[t] = __builtin_amdgcn_mfma_f32_16x16x32_f16(af, bfrag, acc[t], 0, 0, 0);
  }

  // per-lane softmax over 52 n-values + cross-lane combine (lanes sharing r15)
  float mx = -1e30f;
  #pragma unroll
  for (int t = 0; t < 13; ++t)
    mx = fmaxf(mx, fmaxf(fmaxf(acc[t][0], acc[t][1]), fmaxf(acc[t][2], acc[t][3])));
  mx = fmaxf(mx, __shfl_xor(mx, 16));
  mx = fmaxf(mx, __shfl_xor(mx, 32));
  float se = 0.f, te = 0.f;
  #pragma unroll
  for (int t = 0; t < 13; ++t){
    #pragma unroll
    for (int r = 0; r < 4; ++r){
      float d = acc[t][r] - mx;
      float e = __expf(d);
      se += e; te += d*e;
      acc[t][r] = e;
    }
  }
  se += __shfl_xor(se, 16); se += __shfl_xor(se, 32);
  te += __shfl_xor(te, 16); te += __shfl_xor(te, 32);
  const float inv = 1.f / se;
  if (r15 < 12){
    #pragma unroll
    for (int t = 0; t < 13; ++t){
      if (t == 12){
        // cols 196..199 (g==1) are real zeros needed by the E tail; skip g>=2 (beyond stride)
        if (g >= 2) continue;
      }
      h2 w0 = cvt_pk(acc[t][0]*inv, acc[t][1]*inv);
      h2 w1 = cvt_pk(acc[t][2]*inv, acc[t][3]*inv);
      *(h4v*)&As[mhB*200 + t*16 + g*4] = __builtin_shufflevector(w0, w1, 0,1,2,3);
    }
    if (g == 0){
      const float LOGN_INV = 0.18946127f; // 1/ln(196)
      outE[(size_t)b*48 + r15*4 + h] = 1.0f + (te*inv - __logf(se)) * LOGN_INV;
    }
  }
  barrier_lds();

  // ---- E: U[mh][c] = sum_n A[mh][n]*T[n][c] via MFMA + batched ds_read_b64_tr_b16.
  //      All 26 tr-reads issued at once (offset immediates), one lgkmcnt(0), 14 MFMAs.
  //      Result stays in registers; written to LDS only after TT is dead. ----
  f32x4 u0 = {0,0,0,0}, u1 = {0,0,0,0};
  if (h < 3){
    const int arow = h*16 + r15;
    const _Float16* Ab = &As[arow*200 + g*8];
    h8 af0 = *(const h8*)(Ab);
    h8 af1 = *(const h8*)(Ab + 32);
    h8 af2 = *(const h8*)(Ab + 64);
    h8 af3 = *(const h8*)(Ab + 96);
    h8 af4 = *(const h8*)(Ab + 128);
    h8 af5 = *(const h8*)(Ab + 160);
    h4v afT = *(const h4v*)&As[arow*200 + 192 + g*4];
    unsigned A0 = (unsigned)(size_t)&TT[0] + (unsigned)(g*512 + r15*8);
    unsigned At = (unsigned)(size_t)&TT[0] + (unsigned)(12288 + g*256 + r15*8);
    h4v t00,t01,t02,t03, t10,t11,t12,t13, t20,t21,t22,t23,
        t30,t31,t32,t33, t40,t41,t42,t43, t50,t51,t52,t53, tt0,tt1;
    TRRD(t00, A0, 0);     TRRD(t01, A0, 256);   TRRD(t02, A0, 128);   TRRD(t03, A0, 384);
    TRRD(t10, A0, 2048);  TRRD(t11, A0, 2304);  TRRD(t12, A0, 2176);  TRRD(t13, A0, 2432);
    TRRD(t20, A0, 4096);  TRRD(t21, A0, 4352);  TRRD(t22, A0, 4224);  TRRD(t23, A0, 4480);
    TRRD(t30, A0, 6144);  TRRD(t31, A0, 6400);  TRRD(t32, A0, 6272);  TRRD(t33, A0, 6528);
    TRRD(t40, A0, 8192);  TRRD(t41, A0, 8448);  TRRD(t42, A0, 8320);  TRRD(t43, A0, 8576);
    TRRD(t50, A0, 10240); TRRD(t51, A0, 10496); TRRD(t52, A0, 10368); TRRD(t53, A0, 10624);
    TRRD(tt0, At, 0);     TRRD(tt1, At, 128);
    asm volatile("s_waitcnt lgkmcnt(0)" ::: "memory");
    __builtin_amdgcn_sched_barrier(0);
    u0 = __builtin_amdgcn_mfma_f32_16x16x32_f16(af0, SH8(t00,t01), u0, 0, 0, 0);
    u1 = __builtin_amdgcn_mfma_f32_16x16x32_f16(af0, SH8(t02,t03), u1, 0, 0, 0);
    u0 = __builtin_amdgcn_mfma_f32_16x16x32_f16(af1, SH8(t10,t11), u0, 0, 0, 0);
    u1 = __builtin_amdgcn_mfma_f32_16x16x32_f16(af1, SH8(t12,t13), u1, 0, 0, 0);
    u0 = __builtin_amdgcn_mfma_f32_16x16x32_f16(af2, SH8(t20,t21), u0, 0, 0, 0);
    u1 = __builtin_amdgcn_mfma_f32_16x16x32_f16(af2, SH8(t22,t23), u1, 0, 0, 0);
    u0 = __builtin_amdgcn_mfma_f32_16x16x32_f16(af3, SH8(t30,t31), u0, 0, 0, 0);
    u1 = __builtin_amdgcn_mfma_f32_16x16x32_f16(af3, SH8(t32,t33), u1, 0, 0, 0);
    u0 = __builtin_amdgcn_mfma_f32_16x16x32_f16(af4, SH8(t40,t41), u0, 0, 0, 0);
    u1 = __builtin_amdgcn_mfma_f32_16x16x32_f16(af4, SH8(t42,t43), u1, 0, 0, 0);
    u0 = __builtin_amdgcn_mfma_f32_16x16x32_f16(af5, SH8(t50,t51), u0, 0, 0, 0);
    u1 = __builtin_amdgcn_mfma_f32_16x16x32_f16(af5, SH8(t52,t53), u1, 0, 0, 0);
    // tail: n = 192..207 (A cols 196..199 zeros; 200..207 read finite neighbors x TT zeros)
    u0 = __builtin_amdgcn_mfma_f32_16x16x16f16(afT, tt0, u0, 0, 0, 0);
    u1 = __builtin_amdgcn_mfma_f32_16x16x16f16(afT, tt1, u1, 0, 0, 0);
  }

  // ---- C: A_avg, A_maps, top-9 mass. lane -> 4 consecutive n; 3 interleaved DPP chains ----
  {
    const bool act = (lane < 49);
    const int nb4 = lane * 4;
    int K00=0,K01=0,K02=0,K03=0, K10=0,K11=0,K12=0,K13=0, K20=0,K21=0,K22=0,K23=0;
    float mass0=0.f, mass1=0.f, mass2=0.f;
    const int m0 = h, m1 = h+4, m2 = h+8;

    #pragma unroll
    for (int mi = 0; mi < 3; ++mi){
      int m = (mi==0) ? m0 : ((mi==1) ? m1 : m2);
      if (act){
        h4v s0 = *(const h4v*)&As[(     m)*200 + nb4];
        h4v s1 = *(const h4v*)&As[(12 + m)*200 + nb4];
        h4v s2 = *(const h4v*)&As[(24 + m)*200 + nb4];
        h4v s3 = *(const h4v*)&As[(36 + m)*200 + nb4];
        h4v sh = (s0 + s1) + (s2 + s3);          // packed fp16 adds
        float a0 = 0.25f*(float)sh[0], a1 = 0.25f*(float)sh[1];
        float a2 = 0.25f*(float)sh[2], a3 = 0.25f*(float)sh[3];
        float* amrow = outA + (size_t)b*2352 + m*196 + nb4;
        f32x2 o0 = {a0, a1}, o1 = {a2, a3};
        __builtin_nontemporal_store(o0, (f32x2*)amrow);
        __builtin_nontemporal_store(o1, (f32x2*)(amrow + 2));
        int kk0 = (__builtin_bit_cast(int, a0) & ~0xFF) | (lane << 2) | 0;
        int kk1 = (__builtin_bit_cast(int, a1) & ~0xFF) | (lane << 2) | 1;
        int kk2 = (__builtin_bit_cast(int, a2) & ~0xFF) | (lane << 2) | 2;
        int kk3 = (__builtin_bit_cast(int, a3) & ~0xFF) | (lane << 2) | 3;
        if (mi == 0){ K00=kk0; K01=kk1; K02=kk2; K03=kk3; }
        else if (mi == 1){ K10=kk0; K11=kk1; K12=kk2; K13=kk3; }
        else { K20=kk0; K21=kk1; K22=kk2; K23=kk3; }
      }
    }
    #pragma unroll
    for (int k = 0; k < 9; ++k){
      int g0 = wimax_all(max(max(K00,K01), max(K02,K03)));
      int g1 = wimax_all(max(max(K10,K11), max(K12,K13)));
      int g2 = wimax_all(max(max(K20,K21), max(K22,K23)));
      mass0 += __builtin_bit_cast(float, g0 & ~0xFF);
      mass1 += __builtin_bit_cast(float, g1 & ~0xFF);
      mass2 += __builtin_bit_cast(float, g2 & ~0xFF);
      if (lane == ((g0 >> 2) & 63)){
        int q = g0 & 3;
        if (q==0) K00=0; else if (q==1) K01=0; else if (q==2) K02=0; else K03=0;
      }
      if (lane == ((g1 >> 2) & 63)){
        int q = g1 & 3;
        if (q==0) K10=0; else if (q==1) K11=0; else if (q==2) K12=0; else K13=0;
      }
      if (lane == ((g2 >> 2) & 63)){
        int q = g2 & 3;
        if (q==0) K20=0; else if (q==1) K21=0; else if (q==2) K22=0; else K23=0;
      }
    }
    if (lane == 0){
      __builtin_nontemporal_store(mass0, outK + (size_t)b*12 + m0);
      __builtin_nontemporal_store(mass1, outK + (size_t)b*12 + m1);
      __builtin_nontemporal_store(mass2, outK + (size_t)b*12 + m2);
    }
  }
  barrier_lds();   // all TT reads (tr + content) done; TT is dead

  // ---- U-write: spill register U into the dead TT region ----
  if (h < 3){
    #pragma unroll
    for (int r = 0; r < 4; ++r){
      U[(h*16 + g*4 + r)*36 + r15]      = u0[r];
      U[(h*16 + g*4 + r)*36 + 16 + r15] = u1[r];
    }
  }
  barrier_lds();

  // ---- S: S[m][d] = sum_c U[(d>>3)*12+m][c] * Wv[d][c]; write S out + Ss(LDS) ----
  for (int md = tid; md < 384; md += 256){
    int m = md >> 5, d = md & 31, hh = d >> 3;
    const float4* Urow = (const float4*)(U + (hh*12 + m)*36);
    const float4* Wvr  = (const float4*)(Wv + d*32);
    float a = 0.f;
    #pragma unroll
    for (int q = 0; q < 8; ++q) a += dot4(Urow[q], Wvr[q]);
    Ss[md] = a;
    __builtin_nontemporal_store(a, outS + (size_t)b*384 + md);
  }
  barrier_lds();

  // ---- Z: Z[d] = bp[d] + sum_j Wp[d][j] * Ss[j]  (8-lane shuffle reduce) ----
  {
    int d = tid >> 3, j4 = tid & 7;
    const float4* Wp4 = (const float4*)(Wp + d*384);
    const float4* Ss4 = (const float4*)Ss;
    float a = 0.f;
    #pragma unroll
    for (int jj = 0; jj < 12; ++jj){
      int j = j4 + jj*8;
      a += dot4(Wp4[j], Ss4[j]);
    }
    a += __shfl_xor(a, 1);
    a += __shfl_xor(a, 2);
    a += __shfl_xor(a, 4);
    if (j4 == 0)
      __builtin_nontemporal_store(bp[d] + a, outZ + (size_t)b*32 + d);
  }
}

extern "C" void kernel_launch(void* const* d_in, const int* in_sizes, int n_in,
                              void* d_out, int out_size, void* d_ws, size_t ws_size,
                              hipStream_t stream)
{
  const float* T    = (const float*)d_in[0];
  const float* Q    = (const float*)d_in[1];
  const float* Wq   = (const float*)d_in[2];
  const float* Wk   = (const float*)d_in[3];
  const float* Wv   = (const float*)d_in[4];
  const float* Wp   = (const float*)d_in[5];
  const float* bp   = (const float*)d_in[6];
  const float* rpb  = (const float*)d_in[7];
  const float* qc   = (const float*)d_in[8];
  const float* kc   = (const float*)d_in[9];
  _Float16* G16  = (_Float16*)d_ws;
  float* rpbc32  = (float*)((char*)d_ws + 4096);
  float* outp = (float*)d_out;

  prologue_kernel<<<40, 256, 0, stream>>>(Q, Wq, Wk, rpb, qc, kc, G16, rpbc32);
  fused_main<<<4096, 256, 0, stream>>>(T, Wv, Wp, bp, G16, rpbc32, outp);
}

// Round 13
// 70.518 us; speedup vs baseline: 1.0074x; 1.0067x over previous
//
#include <hip/hip_runtime.h>
#include <math.h>

// B=4096, N=196, D=32, M=12, NH=4, DH=8, H=W=14
// outputs (flat f32): Z[4096*32] | A_maps[4096*12*196] | head_energy[4096*12*4] | S[4096*12*32] | topk_mass[4096*12]
// ws layout (bytes): G16 fp16[48*32]·log2e @0 | rpbc32 f32[48*208]·log2e @4096 (pad -60000·log2e)
//                    | Wvp f32[32][32] @44032 (col-interleaved permutation of Wv)

typedef float f32x4 __attribute__((ext_vector_type(4)));
typedef float f32x2 __attribute__((ext_vector_type(2)));
typedef _Float16 h2  __attribute__((ext_vector_type(2)));
typedef _Float16 h4v __attribute__((ext_vector_type(4)));
typedef _Float16 h8  __attribute__((ext_vector_type(8)));
typedef __fp16 fp16x2 __attribute__((ext_vector_type(2)));

#define LOG2E 1.4426950408889634f

__device__ __forceinline__ h2 cvt_pk(float a, float b){
  fp16x2 r = __builtin_amdgcn_cvt_pkrtz(a, b);
  return __builtin_bit_cast(h2, r);
}

__device__ __forceinline__ float dot4(float4 a, float4 b){
  return a.x*b.x + a.y*b.y + a.z*b.z + a.w*b.w;
}

// LDS-only barrier: waits ds ops but leaves global (nontemporal) stores in flight.
__device__ __forceinline__ void barrier_lds(){
  asm volatile("s_waitcnt lgkmcnt(0)" ::: "memory");
  __builtin_amdgcn_s_barrier();
  asm volatile("" ::: "memory");
}

// ---- DPP int-max reduction (topk) ----
template<int CTRL>
__device__ __forceinline__ int idpp(int x, int id){
  return __builtin_amdgcn_update_dpp(id, x, CTRL, 0xF, 0xF, false);
}
__device__ __forceinline__ int wimax_all(int x){
  const int ID = 0;
  x = max(x, idpp<0x111>(x, ID));
  x = max(x, idpp<0x112>(x, ID));
  x = max(x, idpp<0x114>(x, ID));
  x = max(x, idpp<0x118>(x, ID));
  x = max(x, idpp<0x142>(x, ID));
  x = max(x, idpp<0x143>(x, ID));
  return __builtin_amdgcn_readlane(x, 63);
}

// ---------------- prologue: G16 fp16 (·log2e); rpbc32 f32 (·log2e); Wvp permuted ----------------
__global__ void prologue_kernel(const float* __restrict__ Q, const float* __restrict__ Wq,
                                const float* __restrict__ Wk, const float* __restrict__ Wv,
                                const float* __restrict__ rpb,
                                const float* __restrict__ qc, const float* __restrict__ kc,
                                _Float16* __restrict__ G16, float* __restrict__ rpbc32,
                                float* __restrict__ Wvp)
{
  __shared__ float Qp[384];
  const int tid = threadIdx.x;
  const int bid = blockIdx.x;

  if (bid == 0){
    for (int i = tid; i < 384; i += 256){
      int m = i >> 5, d = i & 31;
      float a = 0.f;
      #pragma unroll
      for (int c = 0; c < 32; ++c) a += Q[m*32+c] * Wq[d*32+c];
      Qp[i] = a;
    }
    __syncthreads();
    const float s = 0.35355339059327373f * LOG2E; // 1/sqrt(8) * log2(e)
    for (int i = tid; i < 1536; i += 256){
      int hm = i >> 5, c = i & 31;
      int hh = hm / 12, mm = hm - 12*hh;
      float a = 0.f;
      #pragma unroll
      for (int dh = 0; dh < 8; ++dh) a += Qp[mm*32 + hh*8 + dh] * Wk[(hh*8+dh)*32 + c];
      G16[i] = (_Float16)(a * s);
    }
  }
  if (bid == 1){
    // Wvp[d][cp] = Wv[d][(cp>>1) + ((cp&1)<<4)]  (col-interleave to match U layout)
    for (int i = tid; i < 1024; i += 256){
      int d = i >> 5, cp = i & 31;
      Wvp[i] = Wv[d*32 + (cp>>1) + ((cp&1)<<4)];
    }
  }
  int i = bid*256 + tid;
  if (i < 9984){                       // 48 rows x 208 cols
    int mh = i / 208, n = i - mh*208;
    float v;
    if (n < 196){
      int hh = mh / 12, mm = mh - 12*hh;
      float dy = qc[2*mm]   - kc[2*n];
      float dx = qc[2*mm+1] - kc[2*n+1];
      int iy = (int)rintf(dy) + 13; iy = iy < 0 ? 0 : (iy > 26 ? 26 : iy);
      int ix = (int)rintf(dx) + 13; ix = ix < 0 ? 0 : (ix > 26 ? 26 : ix);
      v = rpb[hh*729 + iy*27 + ix];
    } else {
      v = -60000.0f;                   // pad: exp2 -> 0, never the max
    }
    rpbc32[i] = v * LOG2E;
  }
}

// TT layout: subtiled [nb][cb][4][16] halfs, nb-stride 128 halfs (UNPADDED: every
// [4][16] subtile is 128-B aligned, required by ds_read_b64_tr_b16 tile addressing).
// T[n][c] at (n>>2)*128 + (c>>4)*64 + (n&3)*16 + (c&15).  208 rows (52 nb).
__device__ __forceinline__ int ttoff(int n, int c8){   // c8 = chunk of 8 halfs
  return (n>>2)*128 + ((c8>>1)<<6) + ((n&3)<<4) + ((c8&1)<<3);
}

#define TRRD(dst, base, off) \
  asm volatile("ds_read_b64_tr_b16 %0, %1 offset:" #off : "=v"(dst) : "v"(base))
#define SH8(a, b) __builtin_shufflevector(a, b, 0,1,2,3,4,5,6,7)

// ---------------- fully fused kernel: one block per batch element ----------------
__global__ __launch_bounds__(256, 4) void fused_main(
    const float* __restrict__ T, const float* __restrict__ Wvp, const float* __restrict__ Wp,
    const float* __restrict__ bp, const _Float16* __restrict__ G16,
    const float* __restrict__ rpbc32, float* __restrict__ out)
{
  // TT:13312B @0 | As:19232B @13312 | U:6912B @32544 (DEDICATED - written right after E,
  // overlapping phase C; no barrier needed before the write).  Ss aliases TT @0 after B3.
  // Total LDS 39456B -> 4 blocks/CU.
  __shared__ __align__(128) char smem[39456];
  _Float16* TT = (_Float16*)smem;                 // [52 nb][128] halfs (rows 0..207)
  _Float16* As = (_Float16*)(smem + 13312);       // [48][200] halfs + 16-half guard
  float*    U  = (float*)(smem + 32544);          // [48][36] f32, col-interleaved cp
  float*    Ss = (float*)smem;                    // [384] f32 (alias over dead TT)

  const int b    = blockIdx.x;
  const int tid  = threadIdx.x;
  const int lane = tid & 63;
  const int h    = tid >> 6;       // wave id
  const int r15  = lane & 15;
  const int g    = lane >> 4;

  float* outZ = out;                       // [4096][32]
  float* outA = out + 131072;              // [4096][12][196]
  float* outE = out + 9764864;             // [4096][12][4]
  float* outS = out + 9961472;             // [4096][12][32]
  float* outK = out + 11534336;            // [4096][12]

  // ---- A: stage T -> fp16 subtiled LDS (rows 0..207; rows 196..207 zero) ----
  const float* Tb = T + (size_t)b*6272;
  #pragma unroll
  for (int ii = 0; ii < 3; ++ii){
    int i = tid + ii*256;                  // n < 192
    int n = i >> 2, c8 = i & 3;
    const f32x4* src = (const f32x4*)(Tb + n*32 + c8*8);
    f32x4 v0 = __builtin_nontemporal_load(src);
    f32x4 v1 = __builtin_nontemporal_load(src + 1);
    h2 p0 = cvt_pk(v0[0], v0[1]);
    h2 p1 = cvt_pk(v0[2], v0[3]);
    h2 p2 = cvt_pk(v1[0], v1[1]);
    h2 p3 = cvt_pk(v1[2], v1[3]);
    h4v lo = __builtin_shufflevector(p0, p1, 0,1,2,3);
    h4v hi = __builtin_shufflevector(p2, p3, 0,1,2,3);
    *(h8*)&TT[ttoff(n, c8)] = __builtin_shufflevector(lo, hi, 0,1,2,3,4,5,6,7);
  }
  if (tid < 64){
    int i = 768 + tid;                     // n = 192..207
    int n = i >> 2, c8 = i & 3;
    h8 hv = {0,0,0,0,0,0,0,0};
    if (n < 196){
      const f32x4* src = (const f32x4*)(Tb + n*32 + c8*8);
      f32x4 v0 = __builtin_nontemporal_load(src);
      f32x4 v1 = __builtin_nontemporal_load(src + 1);
      h2 p0 = cvt_pk(v0[0], v0[1]);
      h2 p1 = cvt_pk(v0[2], v0[3]);
      h2 p2 = cvt_pk(v1[0], v1[1]);
      h2 p3 = cvt_pk(v1[2], v1[3]);
      h4v lo = __builtin_shufflevector(p0, p1, 0,1,2,3);
      h4v hi = __builtin_shufflevector(p2, p3, 0,1,2,3);
      hv = __builtin_shufflevector(lo, hi, 0,1,2,3,4,5,6,7);
    }
    *(h8*)&TT[ttoff(n, c8)] = hv;
  }
  // zero the 16-half guard after As row 47 (kills the arow=47,g>=2 tail NaN path)
  if (tid < 2){
    h8 z = {0,0,0,0,0,0,0,0};
    *(h8*)&As[9600 + tid*8] = z;
  }

  // B-frag (G row) + rpb f32 accumulator init (global loads before the barrier)
  const int mhB = h*12 + (r15 < 12 ? r15 : 11);
  h8 bfrag = *(const h8*)(G16 + mhB*32 + g*8);
  f32x4 acc[13];
  #pragma unroll
  for (int t = 0; t < 13; ++t)
    acc[t] = *(const f32x4*)(rpbc32 + mhB*208 + t*16 + g*4);
  barrier_lds();

  // ---- B: content via MFMA (log2e-scaled logits).  n = t*16 + g*4 + r, mh col = r15. ----
  const int rowoff = ((r15>>2)*128) + ((r15&3)<<4) + ((g>>1)<<6) + ((g&1)<<3);
  #pragma unroll
  for (int t = 0; t < 13; ++t){
    h8 af = *(const h8*)&TT[rowoff + t*512];
    acc[t] = __builtin_amdgcn_mfma_f32_16x16x32_f16(af, bfrag, acc[t], 0, 0, 0);
  }

  // per-lane softmax (base-2 domain) + cross-lane combine (lanes sharing r15)
  float mx = -1e30f;
  #pragma unroll
  for (int t = 0; t < 13; ++t)
    mx = fmaxf(mx, fmaxf(fmaxf(acc[t][0], acc[t][1]), fmaxf(acc[t][2], acc[t][3])));
  mx = fmaxf(mx, __shfl_xor(mx, 16));
  mx = fmaxf(mx, __shfl_xor(mx, 32));
  float se = 0.f, te = 0.f;
  #pragma unroll
  for (int t = 0; t < 13; ++t){
    #pragma unroll
    for (int r = 0; r < 4; ++r){
      float d = acc[t][r] - mx;          // log2-domain
      float e = __builtin_amdgcn_exp2f(d);
      se += e; te += d*e;
      acc[t][r] = e;
    }
  }
  se += __shfl_xor(se, 16); se += __shfl_xor(se, 32);
  te += __shfl_xor(te, 16); te += __shfl_xor(te, 32);
  const float inv = 1.f / se;
  if (r15 < 12){
    #pragma unroll
    for (int t = 0; t < 13; ++t){
      if (t == 12){
        if (g >= 2) continue;            // beyond As stride; values are exactly 0
      }
      h2 w0 = cvt_pk(acc[t][0]*inv, acc[t][1]*inv);
      h2 w1 = cvt_pk(acc[t][2]*inv, acc[t][3]*inv);
      *(h4v*)&As[mhB*200 + t*16 + g*4] = __builtin_shufflevector(w0, w1, 0,1,2,3);
    }
    if (g == 0){
      const float LOG2N_INV = 0.13132474f; // ln2/ln(196)
      outE[(size_t)b*48 + r15*4 + h] = 1.0f + (te*inv - __log2f(se)) * LOG2N_INV;
    }
  }
  barrier_lds();

  // ---- E: U[mh][c] = sum_n A[mh][n]*T[n][c] via MFMA + batched ds_read_b64_tr_b16
  //      (waves 0..2), then write U straight to its DEDICATED LDS region (overlaps C). ----
  if (h < 3){
    f32x4 u0 = {0,0,0,0}, u1 = {0,0,0,0};
    const int arow = h*16 + r15;
    const _Float16* Ab = &As[arow*200 + g*8];
    h8 af0 = *(const h8*)(Ab);
    h8 af1 = *(const h8*)(Ab + 32);
    h8 af2 = *(const h8*)(Ab + 64);
    h8 af3 = *(const h8*)(Ab + 96);
    h8 af4 = *(const h8*)(Ab + 128);
    h8 af5 = *(const h8*)(Ab + 160);
    h4v afT = *(const h4v*)&As[arow*200 + 192 + g*4];
    unsigned A0 = (unsigned)(size_t)&TT[0] + (unsigned)(g*512 + r15*8);
    unsigned At = (unsigned)(size_t)&TT[0] + (unsigned)(12288 + g*256 + r15*8);
    h4v t00,t01,t02,t03, t10,t11,t12,t13, t20,t21,t22,t23,
        t30,t31,t32,t33, t40,t41,t42,t43, t50,t51,t52,t53, tt0,tt1;
    TRRD(t00, A0, 0);     TRRD(t01, A0, 256);   TRRD(t02, A0, 128);   TRRD(t03, A0, 384);
    TRRD(t10, A0, 2048);  TRRD(t11, A0, 2304);  TRRD(t12, A0, 2176);  TRRD(t13, A0, 2432);
    TRRD(t20, A0, 4096);  TRRD(t21, A0, 4352);  TRRD(t22, A0, 4224);  TRRD(t23, A0, 4480);
    TRRD(t30, A0, 6144);  TRRD(t31, A0, 6400);  TRRD(t32, A0, 6272);  TRRD(t33, A0, 6528);
    TRRD(t40, A0, 8192);  TRRD(t41, A0, 8448);  TRRD(t42, A0, 8320);  TRRD(t43, A0, 8576);
    TRRD(t50, A0, 10240); TRRD(t51, A0, 10496); TRRD(t52, A0, 10368); TRRD(t53, A0, 10624);
    TRRD(tt0, At, 0);     TRRD(tt1, At, 128);
    asm volatile("s_waitcnt lgkmcnt(0)" ::: "memory");
    __builtin_amdgcn_sched_barrier(0);
    u0 = __builtin_amdgcn_mfma_f32_16x16x32_f16(af0, SH8(t00,t01), u0, 0, 0, 0);
    u1 = __builtin_amdgcn_mfma_f32_16x16x32_f16(af0, SH8(t02,t03), u1, 0, 0, 0);
    u0 = __builtin_amdgcn_mfma_f32_16x16x32_f16(af1, SH8(t10,t11), u0, 0, 0, 0);
    u1 = __builtin_amdgcn_mfma_f32_16x16x32_f16(af1, SH8(t12,t13), u1, 0, 0, 0);
    u0 = __builtin_amdgcn_mfma_f32_16x16x32_f16(af2, SH8(t20,t21), u0, 0, 0, 0);
    u1 = __builtin_amdgcn_mfma_f32_16x16x32_f16(af2, SH8(t22,t23), u1, 0, 0, 0);
    u0 = __builtin_amdgcn_mfma_f32_16x16x32_f16(af3, SH8(t30,t31), u0, 0, 0, 0);
    u1 = __builtin_amdgcn_mfma_f32_16x16x32_f16(af3, SH8(t32,t33), u1, 0, 0, 0);
    u0 = __builtin_amdgcn_mfma_f32_16x16x32_f16(af4, SH8(t40,t41), u0, 0, 0, 0);
    u1 = __builtin_amdgcn_mfma_f32_16x16x32_f16(af4, SH8(t42,t43), u1, 0, 0, 0);
    u0 = __builtin_amdgcn_mfma_f32_16x16x32_f16(af5, SH8(t50,t51), u0, 0, 0, 0);
    u1 = __builtin_amdgcn_mfma_f32_16x16x32_f16(af5, SH8(t52,t53), u1, 0, 0, 0);
    u0 = __builtin_amdgcn_mfma_f32_16x16x16f16(afT, tt0, u0, 0, 0, 0);
    u1 = __builtin_amdgcn_mfma_f32_16x16x16f16(afT, tt1, u1, 0, 0, 0);
    // U-write now (dedicated region, no barrier needed): cp-interleaved pairs
    #pragma unroll
    for (int r = 0; r < 4; ++r){
      f32x2 p = {u0[r], u1[r]};
      *(f32x2*)&U[(h*16 + g*4 + r)*36 + r15*2] = p;
    }
  }

  // ---- C: A_avg, A_maps, top-9 mass. lane -> 4 consecutive n; 3 interleaved DPP chains ----
  {
    const bool act = (lane < 49);
    const int nb4 = lane * 4;
    int K00=0,K01=0,K02=0,K03=0, K10=0,K11=0,K12=0,K13=0, K20=0,K21=0,K22=0,K23=0;
    float mass0=0.f, mass1=0.f, mass2=0.f;
    const int m0 = h, m1 = h+4, m2 = h+8;

    #pragma unroll
    for (int mi = 0; mi < 3; ++mi){
      int m = (mi==0) ? m0 : ((mi==1) ? m1 : m2);
      if (act){
        h4v s0 = *(const h4v*)&As[(     m)*200 + nb4];
        h4v s1 = *(const h4v*)&As[(12 + m)*200 + nb4];
        h4v s2 = *(const h4v*)&As[(24 + m)*200 + nb4];
        h4v s3 = *(const h4v*)&As[(36 + m)*200 + nb4];
        h4v sh = (s0 + s1) + (s2 + s3);          // packed fp16 adds
        float a0 = 0.25f*(float)sh[0], a1 = 0.25f*(float)sh[1];
        float a2 = 0.25f*(float)sh[2], a3 = 0.25f*(float)sh[3];
        float* amrow = outA + (size_t)b*2352 + m*196 + nb4;
        f32x2 o0 = {a0, a1}, o1 = {a2, a3};
        __builtin_nontemporal_store(o0, (f32x2*)amrow);
        __builtin_nontemporal_store(o1, (f32x2*)(amrow + 2));
        int kk0 = (__builtin_bit_cast(int, a0) & ~0xFF) | (lane << 2) | 0;
        int kk1 = (__builtin_bit_cast(int, a1) & ~0xFF) | (lane << 2) | 1;
        int kk2 = (__builtin_bit_cast(int, a2) & ~0xFF) | (lane << 2) | 2;
        int kk3 = (__builtin_bit_cast(int, a3) & ~0xFF) | (lane << 2) | 3;
        if (mi == 0){ K00=kk0; K01=kk1; K02=kk2; K03=kk3; }
        else if (mi == 1){ K10=kk0; K11=kk1; K12=kk2; K13=kk3; }
        else { K20=kk0; K21=kk1; K22=kk2; K23=kk3; }
      }
    }
    #pragma unroll
    for (int k = 0; k < 9; ++k){
      int g0 = wimax_all(max(max(K00,K01), max(K02,K03)));
      int g1 = wimax_all(max(max(K10,K11), max(K12,K13)));
      int g2 = wimax_all(max(max(K20,K21), max(K22,K23)));
      mass0 += __builtin_bit_cast(float, g0 & ~0xFF);
      mass1 += __builtin_bit_cast(float, g1 & ~0xFF);
      mass2 += __builtin_bit_cast(float, g2 & ~0xFF);
      if (lane == ((g0 >> 2) & 63)){
        int q = g0 & 3;
        if (q==0) K00=0; else if (q==1) K01=0; else if (q==2) K02=0; else K03=0;
      }
      if (lane == ((g1 >> 2) & 63)){
        int q = g1 & 3;
        if (q==0) K10=0; else if (q==1) K11=0; else if (q==2) K12=0; else K13=0;
      }
      if (lane == ((g2 >> 2) & 63)){
        int q = g2 & 3;
        if (q==0) K20=0; else if (q==1) K21=0; else if (q==2) K22=0; else K23=0;
      }
    }
    if (lane == 0){
      __builtin_nontemporal_store(mass0, outK + (size_t)b*12 + m0);
      __builtin_nontemporal_store(mass1, outK + (size_t)b*12 + m1);
      __builtin_nontemporal_store(mass2, outK + (size_t)b*12 + m2);
    }
  }
  barrier_lds();   // TT reads done (TT dead), U writes visible

  // ---- S: S[m][d] = sum_cp U[(d>>3)*12+m][cp] * Wvp[d][cp]; write S out + Ss(LDS) ----
  for (int md = tid; md < 384; md += 256){
    int m = md >> 5, d = md & 31, hh = d >> 3;
    const float4* Urow = (const float4*)(U + (hh*12 + m)*36);
    const float4* Wvr  = (const float4*)(Wvp + d*32);
    float a = 0.f;
    #pragma unroll
    for (int q = 0; q < 8; ++q) a += dot4(Urow[q], Wvr[q]);
    Ss[md] = a;
    __builtin_nontemporal_store(a, outS + (size_t)b*384 + md);
  }
  barrier_lds();

  // ---- Z: Z[d] = bp[d] + sum_j Wp[d][j] * Ss[j]  (8-lane shuffle reduce) ----
  {
    int d = tid >> 3, j4 = tid & 7;
    const float4* Wp4 = (const float4*)(Wp + d*384);
    const float4* Ss4 = (const float4*)Ss;
    float a = 0.f;
    #pragma unroll
    for (int jj = 0; jj < 12; ++jj){
      int j = j4 + jj*8;
      a += dot4(Wp4[j], Ss4[j]);
    }
    a += __shfl_xor(a, 1);
    a += __shfl_xor(a, 2);
    a += __shfl_xor(a, 4);
    if (j4 == 0)
      __builtin_nontemporal_store(bp[d] + a, outZ + (size_t)b*32 + d);
  }
}

extern "C" void kernel_launch(void* const* d_in, const int* in_sizes, int n_in,
                              void* d_out, int out_size, void* d_ws, size_t ws_size,
                              hipStream_t stream)
{
  const float* T    = (const float*)d_in[0];
  const float* Q    = (const float*)d_in[1];
  const float* Wq   = (const float*)d_in[2];
  const float* Wk   = (const float*)d_in[3];
  const float* Wv   = (const float*)d_in[4];
  const float* Wp   = (const float*)d_in[5];
  const float* bp   = (const float*)d_in[6];
  const float* rpb  = (const float*)d_in[7];
  const float* qc   = (const float*)d_in[8];
  const float* kc   = (const float*)d_in[9];
  _Float16* G16  = (_Float16*)d_ws;
  float* rpbc32  = (float*)((char*)d_ws + 4096);
  float* Wvp     = (float*)((char*)d_ws + 44032);
  float* outp = (float*)d_out;

  prologue_kernel<<<40, 256, 0, stream>>>(Q, Wq, Wk, Wv, rpb, qc, kc, G16, rpbc32, Wvp);
  fused_main<<<4096, 256, 0, stream>>>(T, Wvp, Wp, bp, G16, rpbc32, outp);
}

// Round 14
// 69.325 us; speedup vs baseline: 1.0247x; 1.0172x over previous
//
#include <hip/hip_runtime.h>
#include <math.h>

// B=4096, N=196, D=32, M=12, NH=4, DH=8, H=W=14
// outputs (flat f32): Z[4096*32] | A_maps[4096*12*196] | head_energy[4096*12*4] | S[4096*12*32] | topk_mass[4096*12]
// ws layout (bytes): G16 fp16[48*32]·log2e @0 | rpbc32 f32[48*208]·log2e @4096 (pad -60000·log2e)
//                    | Wvp f32[32][32] @44032 (col-interleaved permutation of Wv)

typedef float f32x4 __attribute__((ext_vector_type(4)));
typedef float f32x2 __attribute__((ext_vector_type(2)));
typedef _Float16 h2  __attribute__((ext_vector_type(2)));
typedef _Float16 h4v __attribute__((ext_vector_type(4)));
typedef _Float16 h8  __attribute__((ext_vector_type(8)));
typedef __fp16 fp16x2 __attribute__((ext_vector_type(2)));

#define LOG2E 1.4426950408889634f

__device__ __forceinline__ h2 cvt_pk(float a, float b){
  fp16x2 r = __builtin_amdgcn_cvt_pkrtz(a, b);
  return __builtin_bit_cast(h2, r);
}

__device__ __forceinline__ float dot4(float4 a, float4 b){
  return a.x*b.x + a.y*b.y + a.z*b.z + a.w*b.w;
}

// LDS-only barrier: waits ds ops but leaves global (nontemporal) stores in flight.
__device__ __forceinline__ void barrier_lds(){
  asm volatile("s_waitcnt lgkmcnt(0)" ::: "memory");
  __builtin_amdgcn_s_barrier();
  asm volatile("" ::: "memory");
}

// ---- DPP int-max reduction (topk) ----
template<int CTRL>
__device__ __forceinline__ int idpp(int x, int id){
  return __builtin_amdgcn_update_dpp(id, x, CTRL, 0xF, 0xF, false);
}
__device__ __forceinline__ int wimax_all(int x){
  const int ID = 0;
  x = max(x, idpp<0x111>(x, ID));
  x = max(x, idpp<0x112>(x, ID));
  x = max(x, idpp<0x114>(x, ID));
  x = max(x, idpp<0x118>(x, ID));
  x = max(x, idpp<0x142>(x, ID));
  x = max(x, idpp<0x143>(x, ID));
  return __builtin_amdgcn_readlane(x, 63);
}

// ---------------- prologue: G16 fp16 (·log2e); rpbc32 f32 (·log2e); Wvp permuted ----------------
__global__ void prologue_kernel(const float* __restrict__ Q, const float* __restrict__ Wq,
                                const float* __restrict__ Wk, const float* __restrict__ Wv,
                                const float* __restrict__ rpb,
                                const float* __restrict__ qc, const float* __restrict__ kc,
                                _Float16* __restrict__ G16, float* __restrict__ rpbc32,
                                float* __restrict__ Wvp)
{
  __shared__ float Qp[384];
  const int tid = threadIdx.x;
  const int bid = blockIdx.x;

  if (bid == 0){
    for (int i = tid; i < 384; i += 256){
      int m = i >> 5, d = i & 31;
      float a = 0.f;
      #pragma unroll
      for (int c = 0; c < 32; ++c) a += Q[m*32+c] * Wq[d*32+c];
      Qp[i] = a;
    }
    __syncthreads();
    const float s = 0.35355339059327373f * LOG2E; // 1/sqrt(8) * log2(e)
    for (int i = tid; i < 1536; i += 256){
      int hm = i >> 5, c = i & 31;
      int hh = hm / 12, mm = hm - 12*hh;
      float a = 0.f;
      #pragma unroll
      for (int dh = 0; dh < 8; ++dh) a += Qp[mm*32 + hh*8 + dh] * Wk[(hh*8+dh)*32 + c];
      G16[i] = (_Float16)(a * s);
    }
  }
  if (bid == 1){
    // Wvp[d][cp] = Wv[d][(cp>>1) + ((cp&1)<<4)]  (col-interleave to match U layout)
    for (int i = tid; i < 1024; i += 256){
      int d = i >> 5, cp = i & 31;
      Wvp[i] = Wv[d*32 + (cp>>1) + ((cp&1)<<4)];
    }
  }
  int i = bid*256 + tid;
  if (i < 9984){                       // 48 rows x 208 cols
    int mh = i / 208, n = i - mh*208;
    float v;
    if (n < 196){
      int hh = mh / 12, mm = mh - 12*hh;
      float dy = qc[2*mm]   - kc[2*n];
      float dx = qc[2*mm+1] - kc[2*n+1];
      int iy = (int)rintf(dy) + 13; iy = iy < 0 ? 0 : (iy > 26 ? 26 : iy);
      int ix = (int)rintf(dx) + 13; ix = ix < 0 ? 0 : (ix > 26 ? 26 : ix);
      v = rpb[hh*729 + iy*27 + ix];
    } else {
      v = -60000.0f;                   // pad: exp2 -> 0, never contributes
    }
    rpbc32[i] = v * LOG2E;
  }
}

// TT layout: subtiled [nb][cb][4][16] halfs, nb-stride 128 halfs (UNPADDED: every
// [4][16] subtile is 128-B aligned, required by ds_read_b64_tr_b16 tile addressing).
// T[n][c] at (n>>2)*128 + (c>>4)*64 + (n&3)*16 + (c&15).  208 rows (52 nb).
__device__ __forceinline__ int ttoff(int n, int c8){   // c8 = chunk of 8 halfs
  return (n>>2)*128 + ((c8>>1)<<6) + ((n&3)<<4) + ((c8&1)<<3);
}

#define TRRD(dst, base, off) \
  asm volatile("ds_read_b64_tr_b16 %0, %1 offset:" #off : "=v"(dst) : "v"(base))
#define SH8(a, b) __builtin_shufflevector(a, b, 0,1,2,3,4,5,6,7)

// ---------------- fully fused kernel: one block per batch element ----------------
__global__ __launch_bounds__(256, 4) void fused_main(
    const float* __restrict__ T, const float* __restrict__ Wvp, const float* __restrict__ Wp,
    const float* __restrict__ bp, const _Float16* __restrict__ G16,
    const float* __restrict__ rpbc32, float* __restrict__ out)
{
  // TT:13312B @0 | As:19232B @13312 | U:6912B @32544 (DEDICATED - written right after E,
  // overlapping phase C; no barrier needed before the write).  Ss aliases TT @0 after B3.
  // Total LDS 39456B -> 4 blocks/CU.
  __shared__ __align__(128) char smem[39456];
  _Float16* TT = (_Float16*)smem;                 // [52 nb][128] halfs (rows 0..207)
  _Float16* As = (_Float16*)(smem + 13312);       // [48][200] halfs + 16-half guard
  float*    U  = (float*)(smem + 32544);          // [48][36] f32, col-interleaved cp
  float*    Ss = (float*)smem;                    // [384] f32 (alias over dead TT)

  const int b    = blockIdx.x;
  const int tid  = threadIdx.x;
  const int lane = tid & 63;
  const int h    = tid >> 6;       // wave id
  const int r15  = lane & 15;
  const int g    = lane >> 4;

  float* outZ = out;                       // [4096][32]
  float* outA = out + 131072;              // [4096][12][196]
  float* outE = out + 9764864;             // [4096][12][4]
  float* outS = out + 9961472;             // [4096][12][32]
  float* outK = out + 11534336;            // [4096][12]

  // ---- A: stage T -> fp16 subtiled LDS (rows 0..207; rows 196..207 zero) ----
  const float* Tb = T + (size_t)b*6272;
  #pragma unroll
  for (int ii = 0; ii < 3; ++ii){
    int i = tid + ii*256;                  // n < 192
    int n = i >> 2, c8 = i & 3;
    const f32x4* src = (const f32x4*)(Tb + n*32 + c8*8);
    f32x4 v0 = __builtin_nontemporal_load(src);
    f32x4 v1 = __builtin_nontemporal_load(src + 1);
    h2 p0 = cvt_pk(v0[0], v0[1]);
    h2 p1 = cvt_pk(v0[2], v0[3]);
    h2 p2 = cvt_pk(v1[0], v1[1]);
    h2 p3 = cvt_pk(v1[2], v1[3]);
    h4v lo = __builtin_shufflevector(p0, p1, 0,1,2,3);
    h4v hi = __builtin_shufflevector(p2, p3, 0,1,2,3);
    *(h8*)&TT[ttoff(n, c8)] = __builtin_shufflevector(lo, hi, 0,1,2,3,4,5,6,7);
  }
  if (tid < 64){
    int i = 768 + tid;                     // n = 192..207
    int n = i >> 2, c8 = i & 3;
    h8 hv = {0,0,0,0,0,0,0,0};
    if (n < 196){
      const f32x4* src = (const f32x4*)(Tb + n*32 + c8*8);
      f32x4 v0 = __builtin_nontemporal_load(src);
      f32x4 v1 = __builtin_nontemporal_load(src + 1);
      h2 p0 = cvt_pk(v0[0], v0[1]);
      h2 p1 = cvt_pk(v0[2], v0[3]);
      h2 p2 = cvt_pk(v1[0], v1[1]);
      h2 p3 = cvt_pk(v1[2], v1[3]);
      h4v lo = __builtin_shufflevector(p0, p1, 0,1,2,3);
      h4v hi = __builtin_shufflevector(p2, p3, 0,1,2,3);
      hv = __builtin_shufflevector(lo, hi, 0,1,2,3,4,5,6,7);
    }
    *(h8*)&TT[ttoff(n, c8)] = hv;
  }
  // zero the 16-half guard after As row 47 (kills the arow=47,g>=2 tail NaN path)
  if (tid < 2){
    h8 z = {0,0,0,0,0,0,0,0};
    *(h8*)&As[9600 + tid*8] = z;
  }

  // B-frag (G row) + rpb f32 accumulator init (global loads before the barrier)
  const int mhB = h*12 + (r15 < 12 ? r15 : 11);
  h8 bfrag = *(const h8*)(G16 + mhB*32 + g*8);
  f32x4 acc[13];
  #pragma unroll
  for (int t = 0; t < 13; ++t)
    acc[t] = *(const f32x4*)(rpbc32 + mhB*208 + t*16 + g*4);
  barrier_lds();

  // ---- B: content via MFMA (log2e-scaled logits).  n = t*16 + g*4 + r, mh col = r15. ----
  const int rowoff = ((r15>>2)*128) + ((r15&3)<<4) + ((g>>1)<<6) + ((g&1)<<3);
  #pragma unroll
  for (int t = 0; t < 13; ++t){
    h8 af = *(const h8*)&TT[rowoff + t*512];
    acc[t] = __builtin_amdgcn_mfma_f32_16x16x32_f16(af, bfrag, acc[t], 0, 0, 0);
  }

  // per-lane softmax (base-2 domain, NO max-subtraction: |logits| < 1 by construction,
  // pad logits ~ -8.7e4 give exp2 == 0 exactly and fma(x,0,te) == te).
  float se = 0.f, te = 0.f;
  #pragma unroll
  for (int t = 0; t < 13; ++t){
    #pragma unroll
    for (int r = 0; r < 4; ++r){
      float x = acc[t][r];
      float e = __builtin_amdgcn_exp2f(x);
      se += e; te += x*e;
      acc[t][r] = e;
    }
  }
  se += __shfl_xor(se, 16); se += __shfl_xor(se, 32);
  te += __shfl_xor(te, 16); te += __shfl_xor(te, 32);
  const float inv = 1.f / se;
  if (r15 < 12){
    #pragma unroll
    for (int t = 0; t < 13; ++t){
      if (t == 12){
        if (g >= 2) continue;            // beyond As stride; values are exactly 0
      }
      h2 w0 = cvt_pk(acc[t][0]*inv, acc[t][1]*inv);
      h2 w1 = cvt_pk(acc[t][2]*inv, acc[t][3]*inv);
      *(h4v*)&As[mhB*200 + t*16 + g*4] = __builtin_shufflevector(w0, w1, 0,1,2,3);
    }
    if (g == 0){
      const float LOG2N_INV = 0.13132474f; // ln2/ln(196)
      outE[(size_t)b*48 + r15*4 + h] = 1.0f + (te*inv - __log2f(se)) * LOG2N_INV;
    }
  }
  barrier_lds();

  // ---- E: U[mh][c] = sum_n A[mh][n]*T[n][c] via MFMA + batched ds_read_b64_tr_b16
  //      (waves 0..2), then write U straight to its DEDICATED LDS region (overlaps C). ----
  if (h < 3){
    f32x4 u0 = {0,0,0,0}, u1 = {0,0,0,0};
    const int arow = h*16 + r15;
    const _Float16* Ab = &As[arow*200 + g*8];
    h8 af0 = *(const h8*)(Ab);
    h8 af1 = *(const h8*)(Ab + 32);
    h8 af2 = *(const h8*)(Ab + 64);
    h8 af3 = *(const h8*)(Ab + 96);
    h8 af4 = *(const h8*)(Ab + 128);
    h8 af5 = *(const h8*)(Ab + 160);
    h4v afT = *(const h4v*)&As[arow*200 + 192 + g*4];
    unsigned A0 = (unsigned)(size_t)&TT[0] + (unsigned)(g*512 + r15*8);
    unsigned At = (unsigned)(size_t)&TT[0] + (unsigned)(12288 + g*256 + r15*8);
    h4v t00,t01,t02,t03, t10,t11,t12,t13, t20,t21,t22,t23,
        t30,t31,t32,t33, t40,t41,t42,t43, t50,t51,t52,t53, tt0,tt1;
    TRRD(t00, A0, 0);     TRRD(t01, A0, 256);   TRRD(t02, A0, 128);   TRRD(t03, A0, 384);
    TRRD(t10, A0, 2048);  TRRD(t11, A0, 2304);  TRRD(t12, A0, 2176);  TRRD(t13, A0, 2432);
    TRRD(t20, A0, 4096);  TRRD(t21, A0, 4352);  TRRD(t22, A0, 4224);  TRRD(t23, A0, 4480);
    TRRD(t30, A0, 6144);  TRRD(t31, A0, 6400);  TRRD(t32, A0, 6272);  TRRD(t33, A0, 6528);
    TRRD(t40, A0, 8192);  TRRD(t41, A0, 8448);  TRRD(t42, A0, 8320);  TRRD(t43, A0, 8576);
    TRRD(t50, A0, 10240); TRRD(t51, A0, 10496); TRRD(t52, A0, 10368); TRRD(t53, A0, 10624);
    TRRD(tt0, At, 0);     TRRD(tt1, At, 128);
    asm volatile("s_waitcnt lgkmcnt(0)" ::: "memory");
    __builtin_amdgcn_sched_barrier(0);
    u0 = __builtin_amdgcn_mfma_f32_16x16x32_f16(af0, SH8(t00,t01), u0, 0, 0, 0);
    u1 = __builtin_amdgcn_mfma_f32_16x16x32_f16(af0, SH8(t02,t03), u1, 0, 0, 0);
    u0 = __builtin_amdgcn_mfma_f32_16x16x32_f16(af1, SH8(t10,t11), u0, 0, 0, 0);
    u1 = __builtin_amdgcn_mfma_f32_16x16x32_f16(af1, SH8(t12,t13), u1, 0, 0, 0);
    u0 = __builtin_amdgcn_mfma_f32_16x16x32_f16(af2, SH8(t20,t21), u0, 0, 0, 0);
    u1 = __builtin_amdgcn_mfma_f32_16x16x32_f16(af2, SH8(t22,t23), u1, 0, 0, 0);
    u0 = __builtin_amdgcn_mfma_f32_16x16x32_f16(af3, SH8(t30,t31), u0, 0, 0, 0);
    u1 = __builtin_amdgcn_mfma_f32_16x16x32_f16(af3, SH8(t32,t33), u1, 0, 0, 0);
    u0 = __builtin_amdgcn_mfma_f32_16x16x32_f16(af4, SH8(t40,t41), u0, 0, 0, 0);
    u1 = __builtin_amdgcn_mfma_f32_16x16x32_f16(af4, SH8(t42,t43), u1, 0, 0, 0);
    u0 = __builtin_amdgcn_mfma_f32_16x16x32_f16(af5, SH8(t50,t51), u0, 0, 0, 0);
    u1 = __builtin_amdgcn_mfma_f32_16x16x32_f16(af5, SH8(t52,t53), u1, 0, 0, 0);
    u0 = __builtin_amdgcn_mfma_f32_16x16x16f16(afT, tt0, u0, 0, 0, 0);
    u1 = __builtin_amdgcn_mfma_f32_16x16x16f16(afT, tt1, u1, 0, 0, 0);
    // U-write now (dedicated region, no barrier needed): cp-interleaved pairs
    #pragma unroll
    for (int r = 0; r < 4; ++r){
      f32x2 p = {u0[r], u1[r]};
      *(f32x2*)&U[(h*16 + g*4 + r)*36 + r15*2] = p;
    }
  }

  // ---- C: A_avg, A_maps, top-9 mass. lane -> 4 consecutive n; 3 interleaved DPP chains ----
  {
    const bool act = (lane < 49);
    const int nb4 = lane * 4;
    int K00=0,K01=0,K02=0,K03=0, K10=0,K11=0,K12=0,K13=0, K20=0,K21=0,K22=0,K23=0;
    float mass0=0.f, mass1=0.f, mass2=0.f;
    const int m0 = h, m1 = h+4, m2 = h+8;

    #pragma unroll
    for (int mi = 0; mi < 3; ++mi){
      int m = (mi==0) ? m0 : ((mi==1) ? m1 : m2);
      if (act){
        h4v s0 = *(const h4v*)&As[(     m)*200 + nb4];
        h4v s1 = *(const h4v*)&As[(12 + m)*200 + nb4];
        h4v s2 = *(const h4v*)&As[(24 + m)*200 + nb4];
        h4v s3 = *(const h4v*)&As[(36 + m)*200 + nb4];
        h4v sh = (s0 + s1) + (s2 + s3);          // packed fp16 adds
        float a0 = 0.25f*(float)sh[0], a1 = 0.25f*(float)sh[1];
        float a2 = 0.25f*(float)sh[2], a3 = 0.25f*(float)sh[3];
        float* amrow = outA + (size_t)b*2352 + m*196 + nb4;
        f32x2 o0 = {a0, a1}, o1 = {a2, a3};
        __builtin_nontemporal_store(o0, (f32x2*)amrow);
        __builtin_nontemporal_store(o1, (f32x2*)(amrow + 2));
        int kk0 = (__builtin_bit_cast(int, a0) & ~0xFF) | (lane << 2) | 0;
        int kk1 = (__builtin_bit_cast(int, a1) & ~0xFF) | (lane << 2) | 1;
        int kk2 = (__builtin_bit_cast(int, a2) & ~0xFF) | (lane << 2) | 2;
        int kk3 = (__builtin_bit_cast(int, a3) & ~0xFF) | (lane << 2) | 3;
        if (mi == 0){ K00=kk0; K01=kk1; K02=kk2; K03=kk3; }
        else if (mi == 1){ K10=kk0; K11=kk1; K12=kk2; K13=kk3; }
        else { K20=kk0; K21=kk1; K22=kk2; K23=kk3; }
      }
    }
    #pragma unroll
    for (int k = 0; k < 9; ++k){
      int g0 = wimax_all(max(max(K00,K01), max(K02,K03)));
      int g1 = wimax_all(max(max(K10,K11), max(K12,K13)));
      int g2 = wimax_all(max(max(K20,K21), max(K22,K23)));
      mass0 += __builtin_bit_cast(float, g0 & ~0xFF);
      mass1 += __builtin_bit_cast(float, g1 & ~0xFF);
      mass2 += __builtin_bit_cast(float, g2 & ~0xFF);
      if (lane == ((g0 >> 2) & 63)){
        int q = g0 & 3;
        if (q==0) K00=0; else if (q==1) K01=0; else if (q==2) K02=0; else K03=0;
      }
      if (lane == ((g1 >> 2) & 63)){
        int q = g1 & 3;
        if (q==0) K10=0; else if (q==1) K11=0; else if (q==2) K12=0; else K13=0;
      }
      if (lane == ((g2 >> 2) & 63)){
        int q = g2 & 3;
        if (q==0) K20=0; else if (q==1) K21=0; else if (q==2) K22=0; else K23=0;
      }
    }
    if (lane == 0){
      __builtin_nontemporal_store(mass0, outK + (size_t)b*12 + m0);
      __builtin_nontemporal_store(mass1, outK + (size_t)b*12 + m1);
      __builtin_nontemporal_store(mass2, outK + (size_t)b*12 + m2);
    }
  }
  barrier_lds();   // TT reads done (TT dead), U writes visible

  // ---- S: S[m][d] = sum_cp U[(d>>3)*12+m][cp] * Wvp[d][cp]; write S out + Ss(LDS) ----
  for (int md = tid; md < 384; md += 256){
    int m = md >> 5, d = md & 31, hh = d >> 3;
    const float4* Urow = (const float4*)(U + (hh*12 + m)*36);
    const float4* Wvr  = (const float4*)(Wvp + d*32);
    float a = 0.f;
    #pragma unroll
    for (int q = 0; q < 8; ++q) a += dot4(Urow[q], Wvr[q]);
    Ss[md] = a;
    __builtin_nontemporal_store(a, outS + (size_t)b*384 + md);
  }
  barrier_lds();

  // ---- Z: Z[d] = bp[d] + sum_j Wp[d][j] * Ss[j]  (8-lane shuffle reduce) ----
  {
    int d = tid >> 3, j4 = tid & 7;
    const float4* Wp4 = (const float4*)(Wp + d*384);
    const float4* Ss4 = (const float4*)Ss;
    float a = 0.f;
    #pragma unroll
    for (int jj = 0; jj < 12; ++jj){
      int j = j4 + jj*8;
      a += dot4(Wp4[j], Ss4[j]);
    }
    a += __shfl_xor(a, 1);
    a += __shfl_xor(a, 2);
    a += __shfl_xor(a, 4);
    if (j4 == 0)
      __builtin_nontemporal_store(bp[d] + a, outZ + (size_t)b*32 + d);
  }
}

extern "C" void kernel_launch(void* const* d_in, const int* in_sizes, int n_in,
                              void* d_out, int out_size, void* d_ws, size_t ws_size,
                              hipStream_t stream)
{
  const float* T    = (const float*)d_in[0];
  const float* Q    = (const float*)d_in[1];
  const float* Wq   = (const float*)d_in[2];
  const float* Wk   = (const float*)d_in[3];
  const float* Wv   = (const float*)d_in[4];
  const float* Wp   = (const float*)d_in[5];
  const float* bp   = (const float*)d_in[6];
  const float* rpb  = (const float*)d_in[7];
  const float* qc   = (const float*)d_in[8];
  const float* kc   = (const float*)d_in[9];
  _Float16* G16  = (_Float16*)d_ws;
  float* rpbc32  = (float*)((char*)d_ws + 4096);
  float* Wvp     = (float*)((char*)d_ws + 44032);
  float* outp = (float*)d_out;

  prologue_kernel<<<40, 256, 0, stream>>>(Q, Wq, Wk, Wv, rpb, qc, kc, G16, rpbc32, Wvp);
  fused_main<<<4096, 256, 0, stream>>>(T, Wvp, Wp, bp, G16, rpbc32, outp);
}